// Round 1
// baseline (76.204 us; speedup 1.0000x reference)
//
#include <hip/hip_runtime.h>
#include <math.h>

// Problem constants (from reference)
#define BB   4      // batch
#define HH   32     // query heads
#define GG   4      // query groups (also KV heads)
#define HPG  8      // heads per group
#define DD   128    // head dim
#define NCK  128    // number of compressed keys per head
#define SEQ  8192   // key/value sequence length
#define NSEL 16     // selected blocks
#define BLK  64     // block size

// Kernel A: scores -> softmax -> group mean -> top-16 indices (descending, first-max tie-break)
__global__ void topk_select_kernel(const float* __restrict__ query,
                                   const float* __restrict__ ck,
                                   int* __restrict__ idx_out) {
    const int bg = blockIdx.x;       // 0..15  (b*GG + g)
    const int b  = bg / GG;
    const int g  = bg % GG;
    const int t  = threadIdx.x;      // 0..127, the compressed-key index n

    __shared__ float q_sh[DD];
    __shared__ float red[NCK];
    __shared__ float probs[NCK];

    const float scale = 0.08838834764831845f; // 1/sqrt(128)
    float acc = 0.0f;

    for (int j = 0; j < HPG; ++j) {
        const int h = g * HPG + j;
        // load q[b,h,0,:] into LDS
        q_sh[t] = query[(size_t)(b * HH + h) * DD + t];
        __syncthreads();

        // thread t: dot(q, ck[b,h,t,:])
        const float* row = ck + ((size_t)(b * HH + h) * NCK + t) * DD;
        float s = 0.0f;
        #pragma unroll 8
        for (int d = 0; d < DD; ++d) s += q_sh[d] * row[d];
        s *= scale;

        // block max-reduce
        red[t] = s;
        __syncthreads();
        for (int off = 64; off > 0; off >>= 1) {
            if (t < off) red[t] = fmaxf(red[t], red[t + off]);
            __syncthreads();
        }
        const float m = red[0];
        __syncthreads();

        // exp + sum-reduce
        const float e = expf(s - m);
        red[t] = e;
        __syncthreads();
        for (int off = 64; off > 0; off >>= 1) {
            if (t < off) red[t] += red[t + off];
            __syncthreads();
        }
        const float sum = red[0];
        __syncthreads();   // also guards q_sh overwrite next iter

        acc += e / sum;
    }

    probs[t] = acc * 0.125f;   // mean over 8 heads
    __syncthreads();

    // serial top-16: strictly-greater scan ascending => first occurrence of max,
    // emitted in descending value order (matches jax.lax.top_k)
    if (t == 0) {
        const int base = bg * NSEL;
        for (int k = 0; k < NSEL; ++k) {
            float best = -INFINITY;
            int bi = 0;
            for (int n = 0; n < NCK; ++n) {
                if (probs[n] > best) { best = probs[n]; bi = n; }
            }
            idx_out[base + k] = bi;
            probs[bi] = -INFINITY;
        }
    }
}

// Kernel B: gather 64x128 f32 blocks of keys and values into the concatenated output.
__global__ void gather_kernel(const float* __restrict__ keys,
                              const float* __restrict__ values,
                              const int* __restrict__ idx,
                              float* __restrict__ out) {
    const int bid = blockIdx.x;       // ((b*GG+g)*NSEL + s)
    const int s   = bid % NSEL;
    const int bg  = bid / NSEL;       // 0..15
    const int t   = threadIdx.x;      // 0..255

    const int sel = idx[bg * NSEL + s];

    const size_t src_base = ((size_t)bg * SEQ + (size_t)sel * BLK) * DD;
    const size_t dst_base = ((size_t)bg * (NSEL * BLK) + (size_t)s * BLK) * DD;
    const size_t VOFF = (size_t)BB * GG * NSEL * BLK * DD;  // values start in out

    const float4* __restrict__ ksrc = (const float4*)(keys + src_base);
    const float4* __restrict__ vsrc = (const float4*)(values + src_base);
    float4* __restrict__ kdst = (float4*)(out + dst_base);
    float4* __restrict__ vdst = (float4*)(out + VOFF + dst_base);

    // 64*128/4 = 2048 float4 per matrix; 256 threads -> 8 iters each
    #pragma unroll
    for (int i = 0; i < 8; ++i) kdst[i * 256 + t] = ksrc[i * 256 + t];
    #pragma unroll
    for (int i = 0; i < 8; ++i) vdst[i * 256 + t] = vsrc[i * 256 + t];
}

extern "C" void kernel_launch(void* const* d_in, const int* in_sizes, int n_in,
                              void* d_out, int out_size, void* d_ws, size_t ws_size,
                              hipStream_t stream) {
    const float* query  = (const float*)d_in[0];   // (4,32,1,128)
    const float* ck     = (const float*)d_in[1];   // (4,32,128,128)
    const float* keys   = (const float*)d_in[2];   // (4,4,8192,128)
    const float* values = (const float*)d_in[3];   // (4,4,8192,128)
    float* out = (float*)d_out;                    // keys(4,4,1024,128) ++ values(4,4,1024,128)
    int* idx = (int*)d_ws;                         // 256 ints

    topk_select_kernel<<<BB * GG, NCK, 0, stream>>>(query, ck, idx);
    gather_kernel<<<BB * GG * NSEL, 256, 0, stream>>>(keys, values, idx, out);
}

// Round 2
// 42.892 us; speedup vs baseline: 1.7766x; 1.7766x over previous
//
#include <hip/hip_runtime.h>
#include <math.h>

#define BB   4      // batch
#define HH   32     // query heads
#define GG   4      // query groups (also KV heads)
#define HPG  8      // heads per group
#define DD   128    // head dim
#define NCK  128    // number of compressed keys per head
#define SEQ  8192   // key/value sequence length
#define NSEL 16     // selected blocks
#define BLK  64     // block size

// One block per (b,g): 1024 threads = one thread per (head_in_group, compressed_key).
// scores -> per-head softmax -> group mean -> parallel top-16 (lax.top_k semantics).
__global__ __launch_bounds__(1024) void selector_kernel(const float* __restrict__ query,
                                                        const float* __restrict__ ck,
                                                        int* __restrict__ idx_out) {
    const int bg = blockIdx.x;        // 0..15
    const int b  = bg >> 2;
    const int g  = bg & 3;
    const int t  = threadIdx.x;       // 0..1023
    const int j  = t >> 7;            // head within group, 0..7
    const int r  = t & 127;           // compressed-key index, 0..127
    const int h  = g * HPG + j;

    __shared__ float sh[HPG][NCK];    // staging: q, then scores, then exps, then probs
    __shared__ float cand_v[2];
    __shared__ int   cand_i[2];
    __shared__ int   winner;

    // stage q[b,h,:] into LDS (one row per head)
    sh[j][r] = query[(size_t)(b * HH + h) * DD + r];
    __syncthreads();

    // thread (j,r): dot(q[h], ck[b,h,r,:]) via float4
    const float4* q4 = (const float4*)&sh[j][0];
    const float4* k4 = (const float4*)(ck + ((size_t)(b * HH + h) * NCK + r) * DD);
    float s = 0.0f;
    #pragma unroll
    for (int d = 0; d < DD / 4; ++d) {
        float4 a = q4[d], c = k4[d];
        s += a.x * c.x + a.y * c.y + a.z * c.z + a.w * c.w;
    }
    s *= 0.08838834764831845f;        // 1/sqrt(128)
    __syncthreads();                  // done reading q before overwrite

    // per-head max
    sh[j][r] = s;
    __syncthreads();
    for (int off = 64; off > 0; off >>= 1) {
        if (r < off) sh[j][r] = fmaxf(sh[j][r], sh[j][r + off]);
        __syncthreads();
    }
    const float m = sh[j][0];
    __syncthreads();

    // per-head sum of exps
    const float e = expf(s - m);
    sh[j][r] = e;
    __syncthreads();
    for (int off = 64; off > 0; off >>= 1) {
        if (r < off) sh[j][r] += sh[j][r + off];
        __syncthreads();
    }
    const float sum = sh[j][0];
    __syncthreads();

    // probs, then group mean (threads 0..127 own one n each)
    sh[j][r] = (e / sum) * 0.125f;
    __syncthreads();
    float myv = 0.0f;
    if (t < NCK) {
        #pragma unroll
        for (int jj = 0; jj < HPG; ++jj) myv += sh[jj][t];
    }

    // top-16: wave-shuffle argmax over threads 0..127 (2 full waves), ties -> lower index
    for (int k = 0; k < NSEL; ++k) {
        if (t < NCK) {
            float rv = myv;
            int   ri = t;
            #pragma unroll
            for (int off = 1; off < 64; off <<= 1) {
                float ov = __shfl_xor(rv, off);
                int   oi = __shfl_xor(ri, off);
                if (ov > rv || (ov == rv && oi < ri)) { rv = ov; ri = oi; }
            }
            if ((t & 63) == 0) { cand_v[t >> 6] = rv; cand_i[t >> 6] = ri; }
        }
        __syncthreads();
        if (t == 0) {
            const float v0 = cand_v[0], v1 = cand_v[1];
            const int   i0 = cand_i[0], i1 = cand_i[1];
            // wave1 indices are all > wave0 indices, so strict > keeps lower-index ties
            const int wi = (v1 > v0) ? i1 : i0;
            idx_out[bg * NSEL + k] = wi;
            winner = wi;
        }
        __syncthreads();
        if (t < NCK && t == winner) myv = -INFINITY;
    }
}

// One block per (b,g,sel,K-or-V): copy a 64x128 f32 block (2048 float4, 256 threads).
__global__ __launch_bounds__(256) void gather_kernel(const float* __restrict__ keys,
                                                     const float* __restrict__ values,
                                                     const int* __restrict__ idx,
                                                     float* __restrict__ out) {
    const int bid = blockIdx.x;       // 0..511
    const int isV = bid & 1;
    const int bs  = bid >> 1;         // 0..255
    const int s   = bs & (NSEL - 1);
    const int bg  = bs >> 4;          // 0..15
    const int t   = threadIdx.x;      // 0..255

    const int sel = idx[bg * NSEL + s];

    const size_t src_base = ((size_t)bg * SEQ + (size_t)sel * BLK) * DD;
    const size_t dst_base = ((size_t)bg * (NSEL * BLK) + (size_t)s * BLK) * DD;
    const size_t VOFF     = (size_t)BB * GG * NSEL * BLK * DD;

    const float4* s4 = (const float4*)((isV ? values : keys) + src_base);
    float4*       d4 = (float4*)(out + (isV ? VOFF : 0) + dst_base);

    #pragma unroll
    for (int i = 0; i < 8; ++i) d4[i * 256 + t] = s4[i * 256 + t];
}

extern "C" void kernel_launch(void* const* d_in, const int* in_sizes, int n_in,
                              void* d_out, int out_size, void* d_ws, size_t ws_size,
                              hipStream_t stream) {
    const float* query  = (const float*)d_in[0];   // (4,32,1,128)
    const float* ck     = (const float*)d_in[1];   // (4,32,128,128)
    const float* keys   = (const float*)d_in[2];   // (4,4,8192,128)
    const float* values = (const float*)d_in[3];   // (4,4,8192,128)
    float* out = (float*)d_out;
    int* idx = (int*)d_ws;                         // 256 ints

    selector_kernel<<<BB * GG, 1024, 0, stream>>>(query, ck, idx);
    gather_kernel<<<BB * GG * NSEL * 2, 256, 0, stream>>>(keys, values, idx, out);
}

// Round 3
// 27.152 us; speedup vs baseline: 2.8065x; 1.5797x over previous
//
#include <hip/hip_runtime.h>
#include <math.h>

#define BB   4      // batch
#define HH   32     // query heads
#define GG   4      // query groups (also KV heads)
#define HPG  8      // heads per group
#define DD   128    // head dim
#define NCK  128    // number of compressed keys per head
#define SEQ  8192   // key/value sequence length
#define NSEL 16     // selected blocks
#define BLK  64     // block size

// Kernel 1: one block per (b,h). 512 threads = 4 threads per compressed-key row.
// Coalesced dot + wave-shuffle softmax. Writes per-head probs to ws.
__global__ __launch_bounds__(512, 1) void scores_kernel(const float* __restrict__ query,
                                                        const float* __restrict__ ck,
                                                        float* __restrict__ probs_out) {
    const int bh  = blockIdx.x;          // 0..127  (b*HH + h)
    const int t   = threadIdx.x;         // 0..511
    const int r   = t >> 2;              // row 0..127
    const int sub = t & 3;               // quarter of the row
    const int w   = t >> 6;              // wave 0..7

    __shared__ float q_sh[DD];
    __shared__ float wred[8];

    if (t < DD) q_sh[t] = query[(size_t)bh * DD + t];
    __syncthreads();

    // partial dot: 32 contiguous floats per thread
    const float4* q4 = ((const float4*)q_sh) + sub * 8;
    const float4* c4 = (const float4*)(ck + ((size_t)bh * NCK + r) * DD + sub * 32);
    float s = 0.0f;
    #pragma unroll
    for (int i = 0; i < 8; ++i) {
        float4 a = q4[i], c = c4[i];
        s += a.x * c.x + a.y * c.y + a.z * c.z + a.w * c.w;
    }
    // reduce across the 4 threads of the row (bit-identical on all 4 lanes)
    s += __shfl_xor(s, 1);
    s += __shfl_xor(s, 2);
    s *= 0.08838834764831845f;           // 1/sqrt(128)

    // block max: wave butterfly (values duplicated x4 per row -> max unaffected)
    float wm = s;
    #pragma unroll
    for (int off = 1; off < 64; off <<= 1) wm = fmaxf(wm, __shfl_xor(wm, off));
    if ((t & 63) == 0) wred[w] = wm;
    __syncthreads();
    float m = wred[0];
    #pragma unroll
    for (int i = 1; i < 8; ++i) m = fmaxf(m, wred[i]);
    __syncthreads();

    const float e = expf(s - m);

    // block sum: butterfly counts each row 4x -> S4 = 4 * true sum
    float ws_ = e;
    #pragma unroll
    for (int off = 1; off < 64; off <<= 1) ws_ += __shfl_xor(ws_, off);
    if ((t & 63) == 0) wred[w] = ws_;
    __syncthreads();
    float S4 = wred[0];
    #pragma unroll
    for (int i = 1; i < 8; ++i) S4 += wred[i];

    if (sub == 0) probs_out[(size_t)bh * NCK + r] = 4.0f * e / S4;
}

// Kernel 2: one block per (b,g), 128 threads. Mean over 8 heads + top-16
// (lax.top_k semantics: descending, first-occurrence tie-break).
__global__ __launch_bounds__(128) void topk_kernel(const float* __restrict__ probs,
                                                   int* __restrict__ idx_out) {
    const int bg = blockIdx.x;           // 0..15
    const int b  = bg >> 2;
    const int g  = bg & 3;
    const int t  = threadIdx.x;          // 0..127

    __shared__ float cand_v[2];
    __shared__ int   cand_i[2];
    __shared__ int   winner;

    float myv = 0.0f;
    #pragma unroll
    for (int jj = 0; jj < HPG; ++jj)
        myv += probs[(size_t)(b * HH + g * HPG + jj) * NCK + t];
    myv *= 0.125f;

    for (int k = 0; k < NSEL; ++k) {
        float rv = myv;
        int   ri = t;
        #pragma unroll
        for (int off = 1; off < 64; off <<= 1) {
            float ov = __shfl_xor(rv, off);
            int   oi = __shfl_xor(ri, off);
            if (ov > rv || (ov == rv && oi < ri)) { rv = ov; ri = oi; }
        }
        if ((t & 63) == 0) { cand_v[t >> 6] = rv; cand_i[t >> 6] = ri; }
        __syncthreads();
        if (t == 0) {
            // wave1 indices all exceed wave0's, so strict > keeps lower-index ties
            const int wi = (cand_v[1] > cand_v[0]) ? cand_i[1] : cand_i[0];
            idx_out[bg * NSEL + k] = wi;
            winner = wi;
        }
        __syncthreads();
        if (t == winner) myv = -INFINITY;
    }
}

// Kernel 3: one block per (b,g,sel,K-or-V): copy a 64x128 f32 block.
__global__ __launch_bounds__(256) void gather_kernel(const float* __restrict__ keys,
                                                     const float* __restrict__ values,
                                                     const int* __restrict__ idx,
                                                     float* __restrict__ out) {
    const int bid = blockIdx.x;          // 0..511
    const int isV = bid & 1;
    const int bs  = bid >> 1;            // 0..255
    const int s   = bs & (NSEL - 1);
    const int bg  = bs >> 4;             // 0..15
    const int t   = threadIdx.x;         // 0..255

    const int sel = idx[bg * NSEL + s];

    const size_t src_base = ((size_t)bg * SEQ + (size_t)sel * BLK) * DD;
    const size_t dst_base = ((size_t)bg * (NSEL * BLK) + (size_t)s * BLK) * DD;
    const size_t VOFF     = (size_t)BB * GG * NSEL * BLK * DD;

    const float4* s4 = (const float4*)((isV ? values : keys) + src_base);
    float4*       d4 = (float4*)(out + (isV ? VOFF : 0) + dst_base);

    #pragma unroll
    for (int i = 0; i < 8; ++i) d4[i * 256 + t] = s4[i * 256 + t];
}

extern "C" void kernel_launch(void* const* d_in, const int* in_sizes, int n_in,
                              void* d_out, int out_size, void* d_ws, size_t ws_size,
                              hipStream_t stream) {
    const float* query  = (const float*)d_in[0];   // (4,32,1,128)
    const float* ck     = (const float*)d_in[1];   // (4,32,128,128)
    const float* keys   = (const float*)d_in[2];   // (4,4,8192,128)
    const float* values = (const float*)d_in[3];   // (4,4,8192,128)
    float* out = (float*)d_out;

    float* probs = (float*)d_ws;                               // 4*32*128 floats = 64 KB
    int*   idx   = (int*)((char*)d_ws + (size_t)BB * HH * NCK * sizeof(float)); // 256 ints

    scores_kernel<<<BB * HH, 512, 0, stream>>>(query, ck, probs);
    topk_kernel<<<BB * GG, 128, 0, stream>>>(probs, idx);
    gather_kernel<<<BB * GG * NSEL * 2, 256, 0, stream>>>(keys, values, idx, out);
}